// Round 2
// baseline (2704.588 us; speedup 1.0000x reference)
//
#include <hip/hip_runtime.h>

#define DEV __device__ __forceinline__

DEV float4 ld4(const float* p){ return *reinterpret_cast<const float4*>(p); }
DEV void st4(float* p, float4 v){ *reinterpret_cast<float4*>(p) = v; }
DEV float4 relu4(float4 v){ return make_float4(fmaxf(v.x,0.f),fmaxf(v.y,0.f),fmaxf(v.z,0.f),fmaxf(v.w,0.f)); }
DEV void fma4(float4& a, float s, const float4& w){
    a.x = fmaf(s,w.x,a.x); a.y = fmaf(s,w.y,a.y); a.z = fmaf(s,w.z,a.z); a.w = fmaf(s,w.w,a.w);
}

// ---------------- fill rows with a bias pattern ----------------
template<int COUT>
__global__ __launch_bounds__(256)
void fill_bias(float* __restrict__ Y, const float* __restrict__ b, int n_rows){
    constexpr int Q = COUT/4;
    long i = (long)blockIdx.x*256 + threadIdx.x;
    if (i >= (long)n_rows*Q) return;
    int q = (int)(i % Q);
    reinterpret_cast<float4*>(Y)[i] = reinterpret_cast<const float4*>(b)[q];
}

// ---------------- inverse kernel-map build ----------------
__global__ __launch_bounds__(256)
void inv_init(int* __restrict__ inv, long n){
    long i = (long)blockIdx.x*256 + threadIdx.x;
    if (i < n) inv[i] = -1;
}

__global__ __launch_bounds__(256)
void inv_build(const int* __restrict__ in3, const int* __restrict__ out3,
               int* __restrict__ inv, int M, int n_out){
    int k = blockIdx.x;
    long m = (long)blockIdx.y*256 + threadIdx.x;
    if (m >= M) return;
    long e = (long)k*M + m;
    int o = out3[e];
    if (o != n_out) inv[(long)k*n_out + o] = in3[e];  // o unique within offset k
}

// ---------------- conv1: one offset per launch, outputs unique -> plain RMW ----------------
// grid: (cdiv(M1,256), 2 channel-groups); 256 threads, 1 pair/thread, 32 out-ch/thread.
// W loads are wave-uniform (scalar path); x loads vector; no LDS, no atomics.
__global__ __launch_bounds__(256)
void conv1_pass(const float* __restrict__ xF, const float* __restrict__ ctxF,
                const float* __restrict__ Wk,   // W1 + k*128*64
                const int* __restrict__ inL, const int* __restrict__ outL,
                float* __restrict__ Y, int M1, int n_out)
{
    const int blk0 = blockIdx.x*256;
    if (outL[blk0] == n_out) return;          // fully-padded tail block (uniform branch)
    const int m = blk0 + threadIdx.x;
    const int cb = blockIdx.y*32;
    int o = (m < M1) ? outL[m] : n_out;
    const bool valid = (o != n_out);
    const int i = valid ? inL[m] : 0;         // clamped: reads row 0, result discarded
    const float* rx = xF   + (long)i*64;
    const float* rc = ctxF + (long)i*64;
    float* yp = Y + (long)(valid ? o : 0)*64 + cb;
    float4 acc[8];
    #pragma unroll
    for (int q=0;q<8;++q) acc[q] = valid ? ld4(yp+4*q) : make_float4(0,0,0,0);
    #pragma unroll 1
    for (int h=0; h<2; ++h){
        const float* __restrict__ R  = h ? rc : rx;
        const float* __restrict__ Wh = Wk + h*64*64 + cb;
        #pragma unroll 4
        for (int c0=0;c0<64;c0+=4){
            float4 x = ld4(R+c0);
            #pragma unroll
            for (int ii=0;ii<4;++ii){
                float s = reinterpret_cast<const float*>(&x)[ii];
                const float* wr = Wh + (c0+ii)*64;   // uniform address -> s_load
                #pragma unroll
                for (int q=0;q<8;++q){
                    float4 w = ld4(wr+4*q);
                    fma4(acc[q], s, w);
                }
            }
        }
    }
    if (valid){
        #pragma unroll
        for (int q=0;q<8;++q) st4(yp+4*q, acc[q]);
    }
}

// ---------------- 27-offset sparse conv, gather form, no LDS ----------------
// 256 threads, 2 rows/thread -> 512 output rows per block. W loads wave-uniform.
template<int CIN, int COUT, bool RELU_OUT, bool ADD_SRC>
__global__ __launch_bounds__(256)
void gather27(const float* __restrict__ X, int xs,
              const float* __restrict__ W,
              const int* __restrict__ inv, const float* __restrict__ bias,
              const float* __restrict__ SRC,
              float* __restrict__ Y, int ys, int n_out)
{
    constexpr int Q = COUT/4;
    const int j0 = blockIdx.x*512 + threadIdx.x;
    const int j1 = j0 + 256;
    const bool a0 = j0 < n_out, a1 = j1 < n_out;
    float4 acc0[Q], acc1[Q];
    #pragma unroll
    for (int q=0;q<Q;++q){ float4 b4 = ld4(bias+4*q); acc0[q]=b4; acc1[q]=b4; }
    #pragma unroll 1
    for (int k=0;k<27;++k){
        const long kb = (long)k*n_out;
        int b0 = a0 ? inv[kb + j0] : -1;
        int b1 = a1 ? inv[kb + j1] : -1;
        const bool g0 = b0 >= 0, g1 = b1 >= 0;
        if (!__any(g0 || g1)) continue;       // wave-uniform skip
        const float* R0 = X + (long)(g0 ? b0 : 0)*xs;
        const float* R1 = X + (long)(g1 ? b1 : 0)*xs;
        const float* __restrict__ Wk = W + (long)k*CIN*COUT;
        #pragma unroll
        for (int c0=0;c0<CIN;c0+=4){
            float4 x0 = g0 ? ld4(R0+c0) : make_float4(0,0,0,0);
            float4 x1 = g1 ? ld4(R1+c0) : make_float4(0,0,0,0);
            #pragma unroll
            for (int ii=0;ii<4;++ii){
                const float* wr = Wk + (c0+ii)*COUT;  // uniform address -> s_load
                float s0 = reinterpret_cast<const float*>(&x0)[ii];
                float s1 = reinterpret_cast<const float*>(&x1)[ii];
                #pragma unroll
                for (int q=0;q<Q;++q){
                    float4 w = ld4(wr+4*q);
                    fma4(acc0[q], s0, w);
                    fma4(acc1[q], s1, w);
                }
            }
        }
    }
    if (a0){
        float* yp = Y + (long)j0*ys;
        #pragma unroll
        for (int q=0;q<Q;++q){
            float4 v = acc0[q];
            if constexpr (ADD_SRC){
                float4 s = ld4(SRC + (long)j0*64 + 4*q);
                v.x+=s.x; v.y+=s.y; v.z+=s.z; v.w+=s.w;
            }
            if constexpr (RELU_OUT) v = relu4(v);
            st4(yp + 4*q, v);
        }
    }
    if (a1){
        float* yp = Y + (long)j1*ys;
        #pragma unroll
        for (int q=0;q<Q;++q){
            float4 v = acc1[q];
            if constexpr (ADD_SRC){
                float4 s = ld4(SRC + (long)j1*64 + 4*q);
                v.x+=s.x; v.y+=s.y; v.z+=s.z; v.w+=s.w;
            }
            if constexpr (RELU_OUT) v = relu4(v);
            st4(yp + 4*q, v);
        }
    }
}

// ---------------- dense 1x1: D = relu(A @ Wr10 + br10) ----------------
__global__ __launch_bounds__(256)
void dense_t1(const float* __restrict__ A, const float* __restrict__ W,
              const float* __restrict__ b, float* __restrict__ D, int n_out)
{
    const int j = blockIdx.x*256 + threadIdx.x;
    const bool a = j < n_out;
    const float* ar = A + (long)(a ? j : 0)*64;
    float4 d[4];
    #pragma unroll
    for (int q=0;q<4;++q) d[q] = ld4(b+4*q);
    #pragma unroll 4
    for (int c0=0;c0<64;c0+=4){
        float4 x = ld4(ar+c0);
        #pragma unroll
        for (int ii=0;ii<4;++ii){
            float s = reinterpret_cast<const float*>(&x)[ii];
            const float* wr = W + (c0+ii)*16;   // uniform
            #pragma unroll
            for (int q=0;q<4;++q){ float4 w = ld4(wr+4*q); fma4(d[q], s, w); }
        }
    }
    if (a){
        float* dp = D + (long)j*64;  // D lives in C[:,32:48]; row stride 64
        #pragma unroll
        for (int q=0;q<4;++q) st4(dp+4*q, relu4(d[q]));
    }
}

// ---------------- dense 1x1: C[:,32:64] = E @ Wr12 + br12 + A[:,32:64] ----------------
__global__ __launch_bounds__(256)
void path1_k(const float* __restrict__ E, const float* __restrict__ W,
             const float* __restrict__ b, const float* __restrict__ A,
             float* __restrict__ C, int n_out)
{
    const int j = blockIdx.x*256 + threadIdx.x;
    const bool a = j < n_out;
    const long jj = a ? j : 0;
    float e[16];
    #pragma unroll
    for (int q=0;q<4;++q) *reinterpret_cast<float4*>(e+4*q) = ld4(E + jj*16 + 4*q);
    float4 acc[8];
    #pragma unroll
    for (int q=0;q<8;++q){
        float4 bb = ld4(b+4*q);
        float4 s  = ld4(A + jj*64 + 32 + 4*q);
        acc[q] = make_float4(bb.x+s.x, bb.y+s.y, bb.z+s.z, bb.w+s.w);
    }
    #pragma unroll
    for (int c=0;c<16;++c){
        float s = e[c];
        const float* wr = W + c*32;   // uniform
        #pragma unroll
        for (int q=0;q<8;++q){ float4 w = ld4(wr+4*q); fma4(acc[q], s, w); }
    }
    if (a){
        float* cp = C + jj*64 + 32;
        #pragma unroll
        for (int q=0;q<8;++q) st4(cp+4*q, acc[q]);
    }
}

extern "C" void kernel_launch(void* const* d_in, const int* in_sizes, int n_in_cnt,
                              void* d_out, int out_size, void* d_ws, size_t ws_size,
                              hipStream_t stream)
{
    const float* xF   = (const float*)d_in[0];
    const float* ctxF = (const float*)d_in[1];
    const float* W1   = (const float*)d_in[2];
    const float* b1   = (const float*)d_in[3];
    const float* Wr00 = (const float*)d_in[4];
    const float* br00 = (const float*)d_in[5];
    const float* Wr01 = (const float*)d_in[6];
    const float* br01 = (const float*)d_in[7];
    const float* Wr10 = (const float*)d_in[8];
    const float* br10 = (const float*)d_in[9];
    const float* Wr11 = (const float*)d_in[10];
    const float* br11 = (const float*)d_in[11];
    const float* Wr12 = (const float*)d_in[12];
    const float* br12 = (const float*)d_in[13];
    const float* W2   = (const float*)d_in[14];
    const float* b2   = (const float*)d_in[15];
    const int* in1  = (const int*)d_in[16];
    const int* out1 = (const int*)d_in[17];
    const int* in3  = (const int*)d_in[18];
    const int* out3 = (const int*)d_in[19];

    const int n_out = out_size / 8;          // CL = 8
    const int M1 = in_sizes[16] / 8;
    const int M3 = in_sizes[18] / 27;

    float* ws = (float*)d_ws;
    float* A    = ws;                                   // [n_out][64]  h0
    float* B    = ws + (size_t)64*n_out;                // [n_out][16]  relu(sconv00)
    float* C    = ws + (size_t)80*n_out;                // [n_out][64]  concat+residual
    int*   inv3 = (int*)(ws + (size_t)144*n_out);       // [27][n_out]
    float* E    = B;                                    // alias: B dead before E written
    float* D    = C + 32;                               // t1 in C[:,32:48], stride 64
    float* OUT  = (float*)d_out;

    auto cdiv = [](long a, long b){ return (int)((a + b - 1)/b); };

    // inverse kernel map
    inv_init<<<cdiv((long)27*n_out,256),256,0,stream>>>(inv3, (long)27*n_out);
    inv_build<<<dim3(27,cdiv(M3,256)),256,0,stream>>>(in3, out3, inv3, M3, n_out);

    // conv1: A = b1 rows, then 8 sequential unique-output RMW passes (no atomics)
    fill_bias<64><<<cdiv((long)n_out*16,256),256,0,stream>>>(A, b1, n_out);
    for (int k=0;k<8;++k){
        conv1_pass<<<dim3(cdiv(M1,256),2),256,0,stream>>>(
            xF, ctxF, W1 + (long)k*128*64, in1 + (long)k*M1, out1 + (long)k*M1, A, M1, n_out);
    }

    // B = relu(sconv(A, Wr00) + br00)
    gather27<64,16,true,false><<<cdiv(n_out,512),256,0,stream>>>(A, 64, Wr00, inv3, br00, nullptr, B, 16, n_out);
    // D = relu(A @ Wr10 + br10)   (stored in C[:,32:48])
    dense_t1<<<cdiv(n_out,256),256,0,stream>>>(A, Wr10, br10, D, n_out);
    // C[:,0:32] = sconv(B, Wr01) + br01 + A[:,0:32]
    gather27<16,32,false,true><<<cdiv(n_out,512),256,0,stream>>>(B, 16, Wr01, inv3, br01, A, C, 64, n_out);
    // E = relu(sconv(D, Wr11) + br11)
    gather27<16,16,true,false><<<cdiv(n_out,512),256,0,stream>>>(D, 64, Wr11, inv3, br11, nullptr, E, 16, n_out);
    // C[:,32:64] = E @ Wr12 + br12 + A[:,32:64]
    path1_k<<<cdiv(n_out,256),256,0,stream>>>(E, Wr12, br12, A, C, n_out);
    // OUT = sconv(C, W2) + b2
    gather27<64,8,false,false><<<cdiv(n_out,512),256,0,stream>>>(C, 64, W2, inv3, b2, nullptr, OUT, 8, n_out);
}

// Round 3
// 400.671 us; speedup vs baseline: 6.7501x; 6.7501x over previous
//
#include <hip/hip_runtime.h>

#define DEV __device__ __forceinline__

typedef __attribute__((ext_vector_type(8))) short bf16x8;
typedef __attribute__((ext_vector_type(4))) float f32x4;

DEV float4 ld4(const float* p){ return *reinterpret_cast<const float4*>(p); }

DEV unsigned short f2bf(float f){
    union { float f; unsigned u; } v; v.f = f;
    unsigned r = v.u + 0x7fffu + ((v.u >> 16) & 1u);   // round-to-nearest-even
    return (unsigned short)(r >> 16);
}
DEV float bf2f(unsigned short s){
    union { unsigned u; float f; } v; v.u = ((unsigned)s) << 16;
    return v.f;
}

// ---------------- inverse kernel-map build ----------------
__global__ __launch_bounds__(256)
void inv_init(int* __restrict__ inv, long n){
    long i = (long)blockIdx.x*256 + threadIdx.x;
    if (i < n) inv[i] = -1;
}

__global__ __launch_bounds__(256)
void inv_build(const int* __restrict__ inK, const int* __restrict__ outK,
               int* __restrict__ inv, int M, int n_out){
    int k = blockIdx.y;
    int m = blockIdx.x*256 + threadIdx.x;
    if (m >= M) return;
    int o = outK[(long)k*M + m];
    if (o != n_out) inv[(long)k*n_out + o] = inK[(long)k*M + m];  // o unique per offset
}

// ---------------- W -> fragment-layout bf16 conversion ----------------
// F[cc][nt][lane][j] = W[k][cin][cout], cc = k*KC+kc, cin = kc*32 + (lane>>4)*8 + j,
// cout = nt*16 + (lane&15); pad cout >= CR with 0.
__global__ __launch_bounds__(256)
void wfrag_unpaired(const float* __restrict__ W, unsigned short* __restrict__ F,
                    int KC, int NT, int CIN, int CR, int total){
    int idx = blockIdx.x*256 + threadIdx.x;
    if (idx >= total) return;
    int j = idx & 7, l = (idx >> 3) & 63, rest = idx >> 9;
    int nt = rest % NT, cc = rest / NT;
    int k = cc / KC, kc = cc % KC;
    int g = l >> 4, c = l & 15;
    int cin = kc*32 + g*8 + j, cout = nt*16 + c;
    float v = (cout < CR) ? W[((long)k*CIN + cin)*CR + cout] : 0.f;
    F[idx] = f2bf(v);
}

// paired (CIN=16): chunk cc packs offsets 2cc (lane groups 0,1) and 2cc+1 (groups 2,3).
// F[cc][nt][lane][j] = W[koff][cin][cout], koff = 2cc + (g>>1), cin = (g&1)*8 + j; koff>=NKr -> 0.
__global__ __launch_bounds__(256)
void wfrag_paired(const float* __restrict__ W, unsigned short* __restrict__ F,
                  int NKr, int NT, int CR, int total){
    int idx = blockIdx.x*256 + threadIdx.x;
    if (idx >= total) return;
    int j = idx & 7, l = (idx >> 3) & 63, rest = idx >> 9;
    int nt = rest % NT, cc = rest / NT;
    int g = l >> 4, c = l & 15;
    int koff = 2*cc + (g >> 1);
    int cin = (g & 1)*8 + j, cout = nt*16 + c;
    float v = (koff < NKr && cout < CR) ? W[((long)koff*16 + cin)*CR + cout] : 0.f;
    F[idx] = f2bf(v);
}

// ---------------- unified MFMA conv ----------------
// Wave computes a 16-row x (NT*16)-col output tile. A = gathered bf16 rows, B = pre-swizzled Wfrag.
// MODE 0: inv-gather, NK offsets x KC K32-chunks, bf16 X rows of RB bytes
// MODE 1: paired inv-gather (CIN=16): NK chunk-pairs, offset = 2c + (g>>1)
// MODE 2: identity (CIN=64): KC=2 chunks, row = output row
// MODE 3: identity-paired (CIN=16): one chunk, lane groups >=2 are zero-pad
// MODE 4: conv1 inv-gather, A from TWO fp32 arrays (kc<2: xF, else ctxF), cvt in-register
template<int MODE, int NK, int KC, int NT, int RB, bool RELU, int RESBASE,
         bool OUTBF16, int YS, int CB, int CR>
__global__ __launch_bounds__(256)
void mfma_conv(const void* __restrict__ Xv,
               const float* __restrict__ xF, const float* __restrict__ cF,
               const unsigned short* __restrict__ Wf, const int* __restrict__ inv,
               const float* __restrict__ bias, const unsigned short* __restrict__ RES,
               void* __restrict__ Yv, int n_out)
{
    const int lane = threadIdx.x & 63, wave = threadIdx.x >> 6;
    const int tile = blockIdx.x*4 + wave;
    const int jbase = tile*16;
    if (jbase >= n_out) return;
    const int r = lane & 15, g = lane >> 4;
    const int jrow = jbase + r;
    const bool rowok = jrow < n_out;
    const char* X = (const char*)Xv;
    const bf16x8* __restrict__ WF = (const bf16x8*)Wf;
    const bf16x8 az = {0,0,0,0,0,0,0,0};
    f32x4 acc[NT];
    #pragma unroll
    for (int nt=0; nt<NT; ++nt) acc[nt] = f32x4{0.f,0.f,0.f,0.f};

    if constexpr (MODE == 0 || MODE == 4) {
        #pragma unroll 1
        for (int k=0; k<NK; ++k){
            int b = rowok ? inv[(long)k*n_out + jrow] : -1;
            const bool valid = b >= 0;
            if (__any(valid)) {
                #pragma unroll
                for (int kc=0; kc<KC; ++kc){
                    bf16x8 a = az;
                    if constexpr (MODE == 0) {
                        if (valid) a = *(const bf16x8*)(X + (long)b*RB + kc*64 + g*16);
                    } else {
                        if (valid) {
                            const float* s = (kc < 2) ? (xF + (long)b*64 + kc*32 + g*8)
                                                      : (cF + (long)b*64 + (kc-2)*32 + g*8);
                            float4 lo = ld4(s), hi = ld4(s+4);
                            a[0]=(short)f2bf(lo.x); a[1]=(short)f2bf(lo.y);
                            a[2]=(short)f2bf(lo.z); a[3]=(short)f2bf(lo.w);
                            a[4]=(short)f2bf(hi.x); a[5]=(short)f2bf(hi.y);
                            a[6]=(short)f2bf(hi.z); a[7]=(short)f2bf(hi.w);
                        }
                    }
                    #pragma unroll
                    for (int nt=0; nt<NT; ++nt){
                        bf16x8 w = WF[((long)(k*KC+kc)*NT + nt)*64 + lane];
                        acc[nt] = __builtin_amdgcn_mfma_f32_16x16x32_bf16(a, w, acc[nt], 0, 0, 0);
                    }
                }
            }
        }
    } else if constexpr (MODE == 1) {
        #pragma unroll 1
        for (int c=0; c<NK; ++c){
            int koff = 2*c + (g >> 1);
            int b = rowok ? inv[(long)koff*n_out + jrow] : -1;   // row 27 of inv is all -1
            const bool valid = b >= 0;
            if (__any(valid)) {
                bf16x8 a = az;
                if (valid) a = *(const bf16x8*)(X + (long)b*RB + (g&1)*16);
                #pragma unroll
                for (int nt=0; nt<NT; ++nt){
                    bf16x8 w = WF[((long)c*NT + nt)*64 + lane];
                    acc[nt] = __builtin_amdgcn_mfma_f32_16x16x32_bf16(a, w, acc[nt], 0, 0, 0);
                }
            }
        }
    } else if constexpr (MODE == 2) {
        #pragma unroll
        for (int kc=0; kc<2; ++kc){
            bf16x8 a = az;
            if (rowok) a = *(const bf16x8*)(X + (long)jrow*RB + kc*64 + g*16);
            #pragma unroll
            for (int nt=0; nt<NT; ++nt){
                bf16x8 w = WF[((long)kc*NT + nt)*64 + lane];
                acc[nt] = __builtin_amdgcn_mfma_f32_16x16x32_bf16(a, w, acc[nt], 0, 0, 0);
            }
        }
    } else { // MODE 3
        bf16x8 a = az;
        if (rowok && g < 2) a = *(const bf16x8*)(X + (long)jrow*RB + (g&1)*16);
        #pragma unroll
        for (int nt=0; nt<NT; ++nt){
            bf16x8 w = WF[nt*64 + lane];
            acc[nt] = __builtin_amdgcn_mfma_f32_16x16x32_bf16(a, w, acc[nt], 0, 0, 0);
        }
    }

    // epilogue: D layout col = lane&15, row = (lane>>4)*4 + q  [m89-verified]
    float bi[NT];
    #pragma unroll
    for (int nt=0; nt<NT; ++nt){
        int c = nt*16 + r;
        bi[nt] = (c < CR) ? bias[c] : 0.f;
    }
    #pragma unroll
    for (int q=0; q<4; ++q){
        int row = jbase + g*4 + q;
        if (row < n_out){
            #pragma unroll
            for (int nt=0; nt<NT; ++nt){
                int c = nt*16 + r;
                float v = acc[nt][q] + bi[nt];
                if constexpr (RESBASE >= 0) v += bf2f(RES[(long)row*64 + RESBASE + c]);
                if constexpr (RELU) v = fmaxf(v, 0.f);
                if constexpr (OUTBF16) {
                    ((unsigned short*)Yv)[(long)row*YS + CB + c] = f2bf(v);
                } else {
                    if (c < CR) ((float*)Yv)[(long)row*YS + CB + c] = v;
                }
            }
        }
    }
}

extern "C" void kernel_launch(void* const* d_in, const int* in_sizes, int n_in_cnt,
                              void* d_out, int out_size, void* d_ws, size_t ws_size,
                              hipStream_t stream)
{
    const float* xF   = (const float*)d_in[0];
    const float* ctxF = (const float*)d_in[1];
    const float* W1   = (const float*)d_in[2];
    const float* b1   = (const float*)d_in[3];
    const float* Wr00 = (const float*)d_in[4];
    const float* br00 = (const float*)d_in[5];
    const float* Wr01 = (const float*)d_in[6];
    const float* br01 = (const float*)d_in[7];
    const float* Wr10 = (const float*)d_in[8];
    const float* br10 = (const float*)d_in[9];
    const float* Wr11 = (const float*)d_in[10];
    const float* br11 = (const float*)d_in[11];
    const float* Wr12 = (const float*)d_in[12];
    const float* br12 = (const float*)d_in[13];
    const float* W2   = (const float*)d_in[14];
    const float* b2   = (const float*)d_in[15];
    const int* in1  = (const int*)d_in[16];
    const int* out1 = (const int*)d_in[17];
    const int* in3  = (const int*)d_in[18];
    const int* out3 = (const int*)d_in[19];

    const int n_out = out_size / 8;          // CL = 8
    const int M1 = in_sizes[16] / 8;
    const int M3 = in_sizes[18] / 27;

    char* p = (char*)d_ws;
    int* inv3 = (int*)p;                 p += (size_t)28*n_out*4;   // 27 built + 1 pad row (-1)
    int* inv1 = (int*)p;                 p += (size_t)8*n_out*4;
    unsigned short* A = (unsigned short*)p;  p += (size_t)n_out*64*2;   // h, bf16
    unsigned short* B = (unsigned short*)p;  p += (size_t)n_out*16*2;   // relu(sconv00)
    unsigned short* C = (unsigned short*)p;  p += (size_t)n_out*64*2;   // concat+residual
    unsigned short* D = (unsigned short*)p;  p += (size_t)n_out*16*2;   // relu(t1)
    unsigned short* E = (unsigned short*)p;  p += (size_t)n_out*16*2;   // relu(sconv11)
    unsigned short* Wf_c1 = (unsigned short*)p;  p += (size_t)32*4*512*2;  // [8k x 4kc][4nt]
    unsigned short* Wf_00 = (unsigned short*)p;  p += (size_t)54*512*2;
    unsigned short* Wf_2  = (unsigned short*)p;  p += (size_t)54*512*2;
    unsigned short* Wf_01 = (unsigned short*)p;  p += (size_t)14*2*512*2;
    unsigned short* Wf_11 = (unsigned short*)p;  p += (size_t)14*512*2;
    unsigned short* Wf_10 = (unsigned short*)p;  p += (size_t)2*512*2;
    unsigned short* Wf_12 = (unsigned short*)p;  p += (size_t)2*512*2;
    float* OUT = (float*)d_out;

    auto cdiv = [](long a, long b){ return (int)((a + b - 1)/b); };

    // inverse kernel maps (inv3: 28 rows incl. pad, inv1: 8 rows — contiguous init)
    inv_init<<<cdiv((long)36*n_out,256),256,0,stream>>>(inv3, (long)36*n_out);
    inv_build<<<dim3(cdiv(M3,256),27),256,0,stream>>>(in3, out3, inv3, M3, n_out);
    inv_build<<<dim3(cdiv(M1,256),8),256,0,stream>>>(in1, out1, inv1, M1, n_out);

    // weight fragment conversion
    wfrag_unpaired<<<cdiv(32*4*512,256),256,0,stream>>>(W1,   Wf_c1, 4, 4, 128, 64, 32*4*512);
    wfrag_unpaired<<<cdiv(54*512,256),  256,0,stream>>>(Wr00, Wf_00, 2, 1,  64, 16, 54*512);
    wfrag_unpaired<<<cdiv(54*512,256),  256,0,stream>>>(W2,   Wf_2,  2, 1,  64,  8, 54*512);
    wfrag_unpaired<<<cdiv(2*512,256),   256,0,stream>>>(Wr10, Wf_10, 2, 1,  64, 16, 2*512);
    wfrag_paired  <<<cdiv(14*2*512,256),256,0,stream>>>(Wr01, Wf_01, 27, 2, 32, 14*2*512);
    wfrag_paired  <<<cdiv(14*512,256),  256,0,stream>>>(Wr11, Wf_11, 27, 1, 16, 14*512);
    wfrag_paired  <<<cdiv(2*512,256),   256,0,stream>>>(Wr12, Wf_12,  1, 2, 32, 2*512);

    const int grid = cdiv(n_out, 64);   // 4 waves/block, 16 rows/wave

    // conv1: A = bf16( b1 + sum_k X[inv1[k]] @ W1[k] )
    mfma_conv<4, 8,4,4, 0, false, -1, true, 64, 0, 64>
        <<<grid,256,0,stream>>>(nullptr, xF, ctxF, Wf_c1, inv1, b1, nullptr, A, n_out);
    // B = relu(sconv(A, Wr00) + br00)
    mfma_conv<0, 27,2,1, 128, true, -1, true, 16, 0, 16>
        <<<grid,256,0,stream>>>(A, nullptr, nullptr, Wf_00, inv3, br00, nullptr, B, n_out);
    // D = relu(A @ Wr10 + br10)
    mfma_conv<2, 1,2,1, 128, true, -1, true, 16, 0, 16>
        <<<grid,256,0,stream>>>(A, nullptr, nullptr, Wf_10, nullptr, br10, nullptr, D, n_out);
    // C[:,0:32] = sconv(B, Wr01) + br01 + A[:,0:32]
    mfma_conv<1, 14,0,2, 32, false, 0, true, 64, 0, 32>
        <<<grid,256,0,stream>>>(B, nullptr, nullptr, Wf_01, inv3, br01, A, C, n_out);
    // E = relu(sconv(D, Wr11) + br11)
    mfma_conv<1, 14,0,1, 32, true, -1, true, 16, 0, 16>
        <<<grid,256,0,stream>>>(D, nullptr, nullptr, Wf_11, inv3, br11, nullptr, E, n_out);
    // C[:,32:64] = E @ Wr12 + br12 + A[:,32:64]
    mfma_conv<3, 1,0,2, 32, false, 32, true, 64, 32, 32>
        <<<grid,256,0,stream>>>(E, nullptr, nullptr, Wf_12, nullptr, br12, A, C, n_out);
    // OUT = sconv(C, W2) + b2   (fp32, masked to 8 cols)
    mfma_conv<0, 27,2,1, 128, false, -1, false, 8, 0, 8>
        <<<grid,256,0,stream>>>(C, nullptr, nullptr, Wf_2, inv3, b2, nullptr, OUT, n_out);
}

// Round 4
// 352.982 us; speedup vs baseline: 7.6621x; 1.1351x over previous
//
#include <hip/hip_runtime.h>

#define DEV __device__ __forceinline__

typedef __attribute__((ext_vector_type(8))) short bf16x8;
typedef __attribute__((ext_vector_type(4))) float f32x4;

DEV float4 ld4(const float* p){ return *reinterpret_cast<const float4*>(p); }

DEV unsigned short f2bf(float f){
    union { float f; unsigned u; } v; v.f = f;
    unsigned r = v.u + 0x7fffu + ((v.u >> 16) & 1u);   // round-to-nearest-even
    return (unsigned short)(r >> 16);
}
DEV float bf2f(unsigned short s){
    union { unsigned u; float f; } v; v.u = ((unsigned)s) << 16;
    return v.f;
}

// ---------------- inverse kernel-map build ----------------
__global__ __launch_bounds__(256)
void inv_init(int* __restrict__ inv, long n){
    long i = (long)blockIdx.x*256 + threadIdx.x;
    if (i < n) inv[i] = -1;
}

__global__ __launch_bounds__(256)
void inv_build(const int* __restrict__ inK, const int* __restrict__ outK,
               int* __restrict__ inv, int M, int n_out){
    int k = blockIdx.y;
    int m = blockIdx.x*256 + threadIdx.x;
    if (m >= M) return;
    int o = outK[(long)k*M + m];
    if (o != n_out) inv[(long)k*n_out + o] = inK[(long)k*M + m];  // o unique per offset
}

// ---------------- W -> fragment-layout bf16 conversion ----------------
__global__ __launch_bounds__(256)
void wfrag_unpaired(const float* __restrict__ W, unsigned short* __restrict__ F,
                    int KC, int NT, int CIN, int CR, int total){
    int idx = blockIdx.x*256 + threadIdx.x;
    if (idx >= total) return;
    int j = idx & 7, l = (idx >> 3) & 63, rest = idx >> 9;
    int nt = rest % NT, cc = rest / NT;
    int k = cc / KC, kc = cc % KC;
    int g = l >> 4, c = l & 15;
    int cin = kc*32 + g*8 + j, cout = nt*16 + c;
    float v = (cout < CR) ? W[((long)k*CIN + cin)*CR + cout] : 0.f;
    F[idx] = f2bf(v);
}

__global__ __launch_bounds__(256)
void wfrag_paired(const float* __restrict__ W, unsigned short* __restrict__ F,
                  int NKr, int NT, int CR, int total){
    int idx = blockIdx.x*256 + threadIdx.x;
    if (idx >= total) return;
    int j = idx & 7, l = (idx >> 3) & 63, rest = idx >> 9;
    int nt = rest % NT, cc = rest / NT;
    int g = l >> 4, c = l & 15;
    int koff = 2*cc + (g >> 1);
    int cin = (g & 1)*8 + j, cout = nt*16 + c;
    float v = (koff < NKr && cout < CR) ? W[((long)koff*16 + cin)*CR + cout] : 0.f;
    F[idx] = f2bf(v);
}

// ---------------- gather MFMA conv: 2 row-tiles per wave, batched inv preload ----------------
// MODE 0: inv-gather, NK offsets x KC K32-chunks, bf16 X rows of RB bytes
// MODE 1: paired inv-gather (CIN=16): NK chunk-pairs, offset = 2c + (g>>1), pad row 27 = -1
// MODE 4: conv1 inv-gather, A from TWO fp32 arrays (kc<2: xF, else ctxF), cvt in-register
template<int MODE, int NK, int G, int KC, int NT, int RB, bool RELU, int RESBASE,
         bool OUTBF16, int YS, int CB, int CR, int WPE>
__global__ __launch_bounds__(256, WPE)
void mfma_gather(const void* __restrict__ Xv,
                 const float* __restrict__ xF, const float* __restrict__ cF,
                 const unsigned short* __restrict__ Wf, const int* __restrict__ inv,
                 const float* __restrict__ bias, const unsigned short* __restrict__ RES,
                 void* __restrict__ Yv, int n_out)
{
    const int lane = threadIdx.x & 63, wave = threadIdx.x >> 6;
    const int jbase = (blockIdx.x*4 + wave)*32;      // 32 rows per wave
    if (jbase >= n_out) return;
    const int r = lane & 15, g = lane >> 4;
    const int jrow0 = jbase + r, jrow1 = jbase + 16 + r;
    const bool ok0 = jrow0 < n_out, ok1 = jrow1 < n_out;
    const char* X = (const char*)Xv;
    const bf16x8* __restrict__ WF = (const bf16x8*)Wf;
    const bf16x8 az = {0,0,0,0,0,0,0,0};
    f32x4 acc0[NT], acc1[NT];
    #pragma unroll
    for (int nt=0; nt<NT; ++nt){ acc0[nt] = f32x4{0,0,0,0}; acc1[nt] = f32x4{0,0,0,0}; }

    #pragma unroll 1
    for (int g0 = 0; g0 < NK; g0 += G) {
        int b0[G], b1[G];
        #pragma unroll
        for (int kk=0; kk<G; ++kk){
            if constexpr (MODE == 1) {
                int koff = 2*(g0+kk) + (g >> 1);
                b0[kk] = ok0 ? inv[(long)koff*n_out + jrow0] : -1;
                b1[kk] = ok1 ? inv[(long)koff*n_out + jrow1] : -1;
            } else {
                b0[kk] = ok0 ? inv[(long)(g0+kk)*n_out + jrow0] : -1;
                b1[kk] = ok1 ? inv[(long)(g0+kk)*n_out + jrow1] : -1;
            }
        }
        #pragma unroll
        for (int kk=0; kk<G; ++kk){
            const int k = g0 + kk;
            if constexpr (MODE == 1) {
                bf16x8 a0 = az, a1 = az;
                if (b0[kk] >= 0) a0 = *(const bf16x8*)(X + (long)b0[kk]*RB + (g&1)*16);
                if (b1[kk] >= 0) a1 = *(const bf16x8*)(X + (long)b1[kk]*RB + (g&1)*16);
                #pragma unroll
                for (int nt=0; nt<NT; ++nt){
                    bf16x8 w = WF[((long)k*NT + nt)*64 + lane];
                    acc0[nt] = __builtin_amdgcn_mfma_f32_16x16x32_bf16(a0, w, acc0[nt], 0, 0, 0);
                    acc1[nt] = __builtin_amdgcn_mfma_f32_16x16x32_bf16(a1, w, acc1[nt], 0, 0, 0);
                }
            } else {
                #pragma unroll
                for (int kc=0; kc<KC; ++kc){
                    bf16x8 a0 = az, a1 = az;
                    if constexpr (MODE == 0) {
                        if (b0[kk] >= 0) a0 = *(const bf16x8*)(X + (long)b0[kk]*RB + kc*64 + g*16);
                        if (b1[kk] >= 0) a1 = *(const bf16x8*)(X + (long)b1[kk]*RB + kc*64 + g*16);
                    } else { // MODE 4
                        if (b0[kk] >= 0) {
                            const float* s = (kc < 2) ? (xF + (long)b0[kk]*64 + kc*32 + g*8)
                                                      : (cF + (long)b0[kk]*64 + (kc-2)*32 + g*8);
                            float4 lo = ld4(s), hi = ld4(s+4);
                            a0[0]=(short)f2bf(lo.x); a0[1]=(short)f2bf(lo.y);
                            a0[2]=(short)f2bf(lo.z); a0[3]=(short)f2bf(lo.w);
                            a0[4]=(short)f2bf(hi.x); a0[5]=(short)f2bf(hi.y);
                            a0[6]=(short)f2bf(hi.z); a0[7]=(short)f2bf(hi.w);
                        }
                        if (b1[kk] >= 0) {
                            const float* s = (kc < 2) ? (xF + (long)b1[kk]*64 + kc*32 + g*8)
                                                      : (cF + (long)b1[kk]*64 + (kc-2)*32 + g*8);
                            float4 lo = ld4(s), hi = ld4(s+4);
                            a1[0]=(short)f2bf(lo.x); a1[1]=(short)f2bf(lo.y);
                            a1[2]=(short)f2bf(lo.z); a1[3]=(short)f2bf(lo.w);
                            a1[4]=(short)f2bf(hi.x); a1[5]=(short)f2bf(hi.y);
                            a1[6]=(short)f2bf(hi.z); a1[7]=(short)f2bf(hi.w);
                        }
                    }
                    #pragma unroll
                    for (int nt=0; nt<NT; ++nt){
                        bf16x8 w = WF[((long)(k*KC+kc)*NT + nt)*64 + lane];
                        acc0[nt] = __builtin_amdgcn_mfma_f32_16x16x32_bf16(a0, w, acc0[nt], 0, 0, 0);
                        acc1[nt] = __builtin_amdgcn_mfma_f32_16x16x32_bf16(a1, w, acc1[nt], 0, 0, 0);
                    }
                }
            }
        }
    }

    // epilogue: D layout col = lane&15, row = (lane>>4)*4 + q  [m89-verified]
    float bi[NT];
    #pragma unroll
    for (int nt=0; nt<NT; ++nt){
        int c = nt*16 + r;
        bi[nt] = (c < CR) ? bias[c] : 0.f;
    }
    #pragma unroll
    for (int q=0; q<4; ++q){
        int row = jbase + g*4 + q;
        if (row < n_out){
            #pragma unroll
            for (int nt=0; nt<NT; ++nt){
                int c = nt*16 + r;
                float v = acc0[nt][q] + bi[nt];
                if constexpr (RESBASE >= 0) v += bf2f(RES[(long)row*64 + RESBASE + c]);
                if constexpr (RELU) v = fmaxf(v, 0.f);
                if constexpr (OUTBF16) ((unsigned short*)Yv)[(long)row*YS + CB + c] = f2bf(v);
                else if (c < CR)       ((float*)Yv)[(long)row*YS + CB + c] = v;
            }
        }
    }
    #pragma unroll
    for (int q=0; q<4; ++q){
        int row = jbase + 16 + g*4 + q;
        if (row < n_out){
            #pragma unroll
            for (int nt=0; nt<NT; ++nt){
                int c = nt*16 + r;
                float v = acc1[nt][q] + bi[nt];
                if constexpr (RESBASE >= 0) v += bf2f(RES[(long)row*64 + RESBASE + c]);
                if constexpr (RELU) v = fmaxf(v, 0.f);
                if constexpr (OUTBF16) ((unsigned short*)Yv)[(long)row*YS + CB + c] = f2bf(v);
                else if (c < CR)       ((float*)Yv)[(long)row*YS + CB + c] = v;
            }
        }
    }
}

// ---------------- identity-mode MFMA (dense 1x1s): unchanged from round 3 ----------------
// MODE 2: identity (CIN=64); MODE 3: identity-paired (CIN=16), groups >=2 zero
template<int MODE, int NT, int RB, bool RELU, int RESBASE,
         bool OUTBF16, int YS, int CB, int CR>
__global__ __launch_bounds__(256)
void mfma_dense(const void* __restrict__ Xv,
                const unsigned short* __restrict__ Wf,
                const float* __restrict__ bias, const unsigned short* __restrict__ RES,
                void* __restrict__ Yv, int n_out)
{
    const int lane = threadIdx.x & 63, wave = threadIdx.x >> 6;
    const int jbase = (blockIdx.x*4 + wave)*16;
    if (jbase >= n_out) return;
    const int r = lane & 15, g = lane >> 4;
    const int jrow = jbase + r;
    const bool rowok = jrow < n_out;
    const char* X = (const char*)Xv;
    const bf16x8* __restrict__ WF = (const bf16x8*)Wf;
    const bf16x8 az = {0,0,0,0,0,0,0,0};
    f32x4 acc[NT];
    #pragma unroll
    for (int nt=0; nt<NT; ++nt) acc[nt] = f32x4{0,0,0,0};

    if constexpr (MODE == 2) {
        #pragma unroll
        for (int kc=0; kc<2; ++kc){
            bf16x8 a = az;
            if (rowok) a = *(const bf16x8*)(X + (long)jrow*RB + kc*64 + g*16);
            #pragma unroll
            for (int nt=0; nt<NT; ++nt){
                bf16x8 w = WF[((long)kc*NT + nt)*64 + lane];
                acc[nt] = __builtin_amdgcn_mfma_f32_16x16x32_bf16(a, w, acc[nt], 0, 0, 0);
            }
        }
    } else {
        bf16x8 a = az;
        if (rowok && g < 2) a = *(const bf16x8*)(X + (long)jrow*RB + (g&1)*16);
        #pragma unroll
        for (int nt=0; nt<NT; ++nt){
            bf16x8 w = WF[nt*64 + lane];
            acc[nt] = __builtin_amdgcn_mfma_f32_16x16x32_bf16(a, w, acc[nt], 0, 0, 0);
        }
    }

    float bi[NT];
    #pragma unroll
    for (int nt=0; nt<NT; ++nt){
        int c = nt*16 + r;
        bi[nt] = (c < CR) ? bias[c] : 0.f;
    }
    #pragma unroll
    for (int q=0; q<4; ++q){
        int row = jbase + g*4 + q;
        if (row < n_out){
            #pragma unroll
            for (int nt=0; nt<NT; ++nt){
                int c = nt*16 + r;
                float v = acc[nt][q] + bi[nt];
                if constexpr (RESBASE >= 0) v += bf2f(RES[(long)row*64 + RESBASE + c]);
                if constexpr (RELU) v = fmaxf(v, 0.f);
                if constexpr (OUTBF16) ((unsigned short*)Yv)[(long)row*YS + CB + c] = f2bf(v);
                else if (c < CR)       ((float*)Yv)[(long)row*YS + CB + c] = v;
            }
        }
    }
}

extern "C" void kernel_launch(void* const* d_in, const int* in_sizes, int n_in_cnt,
                              void* d_out, int out_size, void* d_ws, size_t ws_size,
                              hipStream_t stream)
{
    const float* xF   = (const float*)d_in[0];
    const float* ctxF = (const float*)d_in[1];
    const float* W1   = (const float*)d_in[2];
    const float* b1   = (const float*)d_in[3];
    const float* Wr00 = (const float*)d_in[4];
    const float* br00 = (const float*)d_in[5];
    const float* Wr01 = (const float*)d_in[6];
    const float* br01 = (const float*)d_in[7];
    const float* Wr10 = (const float*)d_in[8];
    const float* br10 = (const float*)d_in[9];
    const float* Wr11 = (const float*)d_in[10];
    const float* br11 = (const float*)d_in[11];
    const float* Wr12 = (const float*)d_in[12];
    const float* br12 = (const float*)d_in[13];
    const float* W2   = (const float*)d_in[14];
    const float* b2   = (const float*)d_in[15];
    const int* in1  = (const int*)d_in[16];
    const int* out1 = (const int*)d_in[17];
    const int* in3  = (const int*)d_in[18];
    const int* out3 = (const int*)d_in[19];

    const int n_out = out_size / 8;          // CL = 8
    const int M1 = in_sizes[16] / 8;
    const int M3 = in_sizes[18] / 27;

    char* p = (char*)d_ws;
    int* inv3 = (int*)p;                 p += (size_t)28*n_out*4;   // 27 built + 1 pad row (-1)
    int* inv1 = (int*)p;                 p += (size_t)8*n_out*4;
    unsigned short* A = (unsigned short*)p;  p += (size_t)n_out*64*2;   // h, bf16
    unsigned short* B = (unsigned short*)p;  p += (size_t)n_out*16*2;   // relu(sconv00)
    unsigned short* C = (unsigned short*)p;  p += (size_t)n_out*64*2;   // concat+residual
    unsigned short* D = (unsigned short*)p;  p += (size_t)n_out*16*2;   // relu(t1)
    unsigned short* E = (unsigned short*)p;  p += (size_t)n_out*16*2;   // relu(sconv11)
    unsigned short* Wf_c1 = (unsigned short*)p;  p += (size_t)32*4*512*2;
    unsigned short* Wf_00 = (unsigned short*)p;  p += (size_t)54*512*2;
    unsigned short* Wf_2  = (unsigned short*)p;  p += (size_t)54*512*2;
    unsigned short* Wf_01 = (unsigned short*)p;  p += (size_t)14*2*512*2;
    unsigned short* Wf_11 = (unsigned short*)p;  p += (size_t)14*512*2;
    unsigned short* Wf_10 = (unsigned short*)p;  p += (size_t)2*512*2;
    unsigned short* Wf_12 = (unsigned short*)p;  p += (size_t)2*512*2;
    float* OUT = (float*)d_out;

    auto cdiv = [](long a, long b){ return (int)((a + b - 1)/b); };

    // inverse kernel maps
    inv_init<<<cdiv((long)36*n_out,256),256,0,stream>>>(inv3, (long)36*n_out);
    inv_build<<<dim3(cdiv(M3,256),27),256,0,stream>>>(in3, out3, inv3, M3, n_out);
    inv_build<<<dim3(cdiv(M1,256),8),256,0,stream>>>(in1, out1, inv1, M1, n_out);

    // weight fragment conversion
    wfrag_unpaired<<<cdiv(32*4*512,256),256,0,stream>>>(W1,   Wf_c1, 4, 4, 128, 64, 32*4*512);
    wfrag_unpaired<<<cdiv(54*512,256),  256,0,stream>>>(Wr00, Wf_00, 2, 1,  64, 16, 54*512);
    wfrag_unpaired<<<cdiv(54*512,256),  256,0,stream>>>(W2,   Wf_2,  2, 1,  64,  8, 54*512);
    wfrag_unpaired<<<cdiv(2*512,256),   256,0,stream>>>(Wr10, Wf_10, 2, 1,  64, 16, 2*512);
    wfrag_paired  <<<cdiv(14*2*512,256),256,0,stream>>>(Wr01, Wf_01, 27, 2, 32, 14*2*512);
    wfrag_paired  <<<cdiv(14*512,256),  256,0,stream>>>(Wr11, Wf_11, 27, 1, 16, 14*512);
    wfrag_paired  <<<cdiv(2*512,256),   256,0,stream>>>(Wr12, Wf_12,  1, 2, 32, 2*512);

    const int grid_g = cdiv(n_out, 128);   // 4 waves/block, 32 rows/wave
    const int grid_d = cdiv(n_out, 64);    // 4 waves/block, 16 rows/wave

    // conv1: A = bf16( b1 + sum_k [xF|ctxF][inv1[k]] @ W1[k] )
    mfma_gather<4, 8,8,4,4, 0, false, -1, true, 64, 0, 64, 3>
        <<<grid_g,256,0,stream>>>(nullptr, xF, ctxF, Wf_c1, inv1, b1, nullptr, A, n_out);
    // B = relu(sconv(A, Wr00) + br00)
    mfma_gather<0, 27,9,2,1, 128, true, -1, true, 16, 0, 16, 4>
        <<<grid_g,256,0,stream>>>(A, nullptr, nullptr, Wf_00, inv3, br00, nullptr, B, n_out);
    // D = relu(A @ Wr10 + br10)
    mfma_dense<2, 1, 128, true, -1, true, 16, 0, 16>
        <<<grid_d,256,0,stream>>>(A, Wf_10, br10, nullptr, D, n_out);
    // C[:,0:32] = sconv(B, Wr01) + br01 + A[:,0:32]
    mfma_gather<1, 14,7,0,2, 32, false, 0, true, 64, 0, 32, 4>
        <<<grid_g,256,0,stream>>>(B, nullptr, nullptr, Wf_01, inv3, br01, A, C, n_out);
    // E = relu(sconv(D, Wr11) + br11)
    mfma_gather<1, 14,7,0,1, 32, true, -1, true, 16, 0, 16, 4>
        <<<grid_g,256,0,stream>>>(D, nullptr, nullptr, Wf_11, inv3, br11, nullptr, E, n_out);
    // C[:,32:64] = E @ Wr12 + br12 + A[:,32:64]
    mfma_dense<3, 2, 32, false, 32, true, 64, 32, 32>
        <<<grid_d,256,0,stream>>>(E, Wf_12, br12, A, C, n_out);
    // OUT = sconv(C, W2) + b2   (fp32, masked to 8 cols)
    mfma_gather<0, 27,9,2,1, 128, false, -1, false, 8, 0, 8, 4>
        <<<grid_g,256,0,stream>>>(C, nullptr, nullptr, Wf_2, inv3, b2, nullptr, OUT, n_out);
}